// Round 2
// baseline (123.135 us; speedup 1.0000x reference)
//
#include <hip/hip_runtime.h>

// FeedForwardQuantum: out = relu(cos(x+theta) @ W1 + b1) @ W2 + b2
// x: [B,S,E=8] fp32, W1: [8,32], W2: [32,8]. 524288 tokens of 8 floats.
//
// R2 design: weights/biases/theta are wave-uniform -> read via uniform
// (constant-offset) loads so the compiler emits s_load into SGPRs through
// the scalar K$ pipe. v_fmac_f32 vdst, sgpr, vgpr consumes them directly
// (1 SGPR operand per VALU inst is legal). No LDS, no __syncthreads.
// TOKT=2 -> 262144 threads, 1024 blocks, 4 waves/SIMD for latency hiding.

#define TPB 256
#define TOKT 2

__global__ __launch_bounds__(TPB, 4) void ffq_kernel(
    const float4* __restrict__ xv,      // x as float4 pairs: token g -> xv[2g], xv[2g+1]
    const float*  __restrict__ theta,   // [8]
    const float*  __restrict__ w1,      // [8][32] row-major
    const float*  __restrict__ b1,      // [32]
    const float*  __restrict__ w2,      // [32][8] row-major
    const float*  __restrict__ b2,      // [8]
    float4*       __restrict__ outv,    // out as float4 pairs
    int ntok)
{
    const int base   = blockIdx.x * TPB + threadIdx.x;
    const int stride = gridDim.x * TPB;

    float q[TOKT][8];
    float o[TOKT][8];

    // Issue all global x loads first (ILP), then cos.
    float4 a[TOKT], c[TOKT];
#pragma unroll
    for (int t = 0; t < TOKT; ++t) {
        int g = base + t * stride;
        if (g < ntok) {
            a[t] = xv[2 * g];
            c[t] = xv[2 * g + 1];
        } else {
            a[t] = make_float4(0.f, 0.f, 0.f, 0.f);
            c[t] = make_float4(0.f, 0.f, 0.f, 0.f);
        }
    }

#pragma unroll
    for (int t = 0; t < TOKT; ++t) {
        q[t][0] = __cosf(a[t].x + theta[0]);
        q[t][1] = __cosf(a[t].y + theta[1]);
        q[t][2] = __cosf(a[t].z + theta[2]);
        q[t][3] = __cosf(a[t].w + theta[3]);
        q[t][4] = __cosf(c[t].x + theta[4]);
        q[t][5] = __cosf(c[t].y + theta[5]);
        q[t][6] = __cosf(c[t].z + theta[6]);
        q[t][7] = __cosf(c[t].w + theta[7]);
#pragma unroll
        for (int e = 0; e < 8; ++e) o[t][e] = b2[e];
    }

    // Fully unrolled: every weight index is a compile-time constant ->
    // uniform s_load, FMAs read the SGPR directly.
#pragma unroll
    for (int f = 0; f < 32; ++f) {
        const float bb = b1[f];
        float wa[8], wb[8];
#pragma unroll
        for (int e = 0; e < 8; ++e) wa[e] = w1[e * 32 + f];   // W1 column f
#pragma unroll
        for (int e = 0; e < 8; ++e) wb[e] = w2[f * 8 + e];    // W2 row f
#pragma unroll
        for (int t = 0; t < TOKT; ++t) {
            float h = bb;
#pragma unroll
            for (int e = 0; e < 8; ++e) h = fmaf(q[t][e], wa[e], h);
            h = fmaxf(h, 0.0f);
#pragma unroll
            for (int e = 0; e < 8; ++e) o[t][e] = fmaf(h, wb[e], o[t][e]);
        }
    }

#pragma unroll
    for (int t = 0; t < TOKT; ++t) {
        int g = base + t * stride;
        if (g < ntok) {
            outv[2 * g]     = make_float4(o[t][0], o[t][1], o[t][2], o[t][3]);
            outv[2 * g + 1] = make_float4(o[t][4], o[t][5], o[t][6], o[t][7]);
        }
    }
}

extern "C" void kernel_launch(void* const* d_in, const int* in_sizes, int n_in,
                              void* d_out, int out_size, void* d_ws, size_t ws_size,
                              hipStream_t stream) {
    const float* x     = (const float*)d_in[0];
    const float* theta = (const float*)d_in[1];
    const float* w1    = (const float*)d_in[2];
    const float* b1    = (const float*)d_in[3];
    const float* w2    = (const float*)d_in[4];
    const float* b2    = (const float*)d_in[5];
    float* out = (float*)d_out;

    const int ntok = in_sizes[0] / 8;  // B*S tokens
    const int total_threads = (ntok + TOKT - 1) / TOKT;
    const int grid = (total_threads + TPB - 1) / TPB;

    ffq_kernel<<<grid, TPB, 0, stream>>>(
        (const float4*)x, theta, w1, b1, w2, b2, (float4*)out, ntok);
}